// Round 1
// baseline (703.184 us; speedup 1.0000x reference)
//
#include <hip/hip_runtime.h>
#include <hip/hip_bf16.h>

constexpr int FDIM = 128;

// ---------------- CSR build ----------------

__global__ __launch_bounds__(256) void k_degree(const int* __restrict__ dst, int* __restrict__ deg, int E){
    int e = blockIdx.x*256 + threadIdx.x;
    if (e < E) atomicAdd(&deg[dst[e]], 1);
}

__global__ __launch_bounds__(256) void k_scan1(const int* __restrict__ deg, int* __restrict__ partial,
                                               int* __restrict__ bsum, int N){
    __shared__ int s[256];
    int i = blockIdx.x*256 + threadIdx.x;
    int v = (i < N) ? deg[i] : 0;
    s[threadIdx.x] = v;
    __syncthreads();
    for (int ofs = 1; ofs < 256; ofs <<= 1){
        int add = (threadIdx.x >= ofs) ? s[threadIdx.x - ofs] : 0;
        __syncthreads();
        s[threadIdx.x] += add;
        __syncthreads();
    }
    if (i < N) partial[i] = s[threadIdx.x];
    if (threadIdx.x == 255) bsum[blockIdx.x] = s[255];
}

__global__ void k_scan2(int* __restrict__ bsum, int nb){
    if (threadIdx.x == 0 && blockIdx.x == 0){
        int run = 0;
        for (int b = 0; b < nb; b++){ int v = bsum[b]; bsum[b] = run; run += v; }
    }
}

__global__ __launch_bounds__(256) void k_scan3(const int* __restrict__ partial, const int* __restrict__ deg,
                                               const int* __restrict__ bsum, int* __restrict__ off,
                                               int* __restrict__ cursor, int N){
    int i = blockIdx.x*256 + threadIdx.x;
    if (i < N){
        int o = partial[i] - deg[i] + bsum[blockIdx.x];  // exclusive
        off[i] = o;
        cursor[i] = o;
    }
}

__global__ __launch_bounds__(256) void k_fill(const int* __restrict__ src, const int* __restrict__ dst,
                                              int* __restrict__ cursor, int* __restrict__ csr, int E){
    int e = blockIdx.x*256 + threadIdx.x;
    if (e < E){
        int p = atomicAdd(&cursor[dst[e]], 1);
        csr[p] = src[e];
    }
}

// ---------------- mean aggregation: one wave per node ----------------

__global__ __launch_bounds__(256) void k_aggregate(const float* __restrict__ feat, const int* __restrict__ csr,
                                                   const int* __restrict__ off, const int* __restrict__ deg,
                                                   float* __restrict__ agg, int N){
    int node = (blockIdx.x*256 + threadIdx.x) >> 6;
    int lane = threadIdx.x & 63;
    if (node >= N) return;
    int o = off[node], d = deg[node];
    float a0 = 0.f, a1 = 0.f;
    for (int base = 0; base < d; base += 64){
        int cnt = min(64, d - base);
        int idx = (lane < cnt) ? csr[o + base + lane] : 0;   // coalesced batch of indices
        for (int j = 0; j < cnt; j++){
            int s = __shfl(idx, j);                          // wave-uniform broadcast
            float2 v = *(const float2*)(feat + (size_t)s*FDIM + lane*2);
            a0 += v.x; a1 += v.y;
        }
    }
    float inv = 1.f / (float)(d > 1 ? d : 1);
    float2 r; r.x = a0 * inv; r.y = a1 * inv;
    *(float2*)(agg + (size_t)node*FDIM + lane*2) = r;
}

// ---------------- fused dual-input linear (+bias, optional L2-rownorm, optional relu) ----------------
// out[n,:] = post( A1[n,:] @ W1^T + A2[n,:] @ W2^T + bias )
// W rows have stride ldw (so a slice of a wider concat-weight works).

template<int NOUT, bool NORM, bool RELU>
__global__ __launch_bounds__(256) void k_linear(
    const float* __restrict__ A1, const float* __restrict__ A2,
    const float* __restrict__ W1, const float* __restrict__ W2, int ldw,
    const float* __restrict__ bias, float* __restrict__ out, int N)
{
    constexpr int CT = NOUT / 4;   // threads covering one row's columns (4 cols each)
    constexpr int G  = 256 / CT;   // row-groups per block
    constexpr int MR = 64 / G;     // rows per thread
    __shared__ __align__(16) float As[2][64][FDIM];  // 64 KB

    const int t  = threadIdx.x;
    const int c  = t % CT;
    const int g  = t / CT;
    const int nb = blockIdx.x * 64;

    // stage A1, A2 tiles (zero-padded past N)
    {
        const float* S0 = A1 + (size_t)nb * FDIM;
        const float* S1 = A2 + (size_t)nb * FDIM;
        #pragma unroll
        for (int a = 0; a < 2; a++){
            const float* S = a ? S1 : S0;
            #pragma unroll
            for (int i = 0; i < 8; i++){
                int fl  = (i*256 + t) * 4;
                int row = fl >> 7;          // / FDIM
                int col = fl & (FDIM - 1);
                float4 v = make_float4(0.f, 0.f, 0.f, 0.f);
                if (nb + row < N) v = *(const float4*)(S + (size_t)row*FDIM + col);
                *(float4*)&As[a][row][col] = v;
            }
        }
    }
    __syncthreads();

    float acc[MR][4];
    #pragma unroll
    for (int m = 0; m < MR; m++){ acc[m][0]=0.f; acc[m][1]=0.f; acc[m][2]=0.f; acc[m][3]=0.f; }

    #pragma unroll
    for (int a = 0; a < 2; a++){
        const float* W  = a ? W2 : W1;
        const float* wr0 = W + (size_t)(c       ) * ldw;
        const float* wr1 = W + (size_t)(c +   CT) * ldw;
        const float* wr2 = W + (size_t)(c + 2*CT) * ldw;
        const float* wr3 = W + (size_t)(c + 3*CT) * ldw;
        for (int k0 = 0; k0 < FDIM; k0 += 4){
            float4 w0 = *(const float4*)(wr0 + k0);
            float4 w1 = *(const float4*)(wr1 + k0);
            float4 w2 = *(const float4*)(wr2 + k0);
            float4 w3 = *(const float4*)(wr3 + k0);
            #pragma unroll
            for (int m = 0; m < MR; m++){
                float4 av = *(const float4*)&As[a][g*MR + m][k0];   // wave-broadcast LDS read
                acc[m][0] += av.x*w0.x + av.y*w0.y + av.z*w0.z + av.w*w0.w;
                acc[m][1] += av.x*w1.x + av.y*w1.y + av.z*w1.z + av.w*w1.w;
                acc[m][2] += av.x*w2.x + av.y*w2.y + av.z*w2.z + av.w*w2.w;
                acc[m][3] += av.x*w3.x + av.y*w3.y + av.z*w3.z + av.w*w3.w;
            }
        }
    }

    float b0 = bias[c], b1 = bias[c+CT], b2 = bias[c+2*CT], b3 = bias[c+3*CT];
    #pragma unroll
    for (int m = 0; m < MR; m++){
        acc[m][0] += b0; acc[m][1] += b1; acc[m][2] += b2; acc[m][3] += b3;
        if (NORM){
            float ss = acc[m][0]*acc[m][0] + acc[m][1]*acc[m][1]
                     + acc[m][2]*acc[m][2] + acc[m][3]*acc[m][3];
            #pragma unroll
            for (int mask = CT/2; mask >= 1; mask >>= 1) ss += __shfl_xor(ss, mask);
            float inv = 1.f / fmaxf(sqrtf(ss), 1e-12f);
            acc[m][0]*=inv; acc[m][1]*=inv; acc[m][2]*=inv; acc[m][3]*=inv;
        }
        if (RELU){
            acc[m][0]=fmaxf(acc[m][0],0.f); acc[m][1]=fmaxf(acc[m][1],0.f);
            acc[m][2]=fmaxf(acc[m][2],0.f); acc[m][3]=fmaxf(acc[m][3],0.f);
        }
        int row = nb + g*MR + m;
        if (row < N){
            float* o = out + (size_t)row * NOUT;
            o[c]      = acc[m][0];
            o[c+CT]   = acc[m][1];
            o[c+2*CT] = acc[m][2];
            o[c+3*CT] = acc[m][3];
        }
    }
}

// ---------------- launch ----------------

extern "C" void kernel_launch(void* const* d_in, const int* in_sizes, int n_in,
                              void* d_out, int out_size, void* d_ws, size_t ws_size,
                              hipStream_t stream)
{
    const float* x    = (const float*)d_in[0];
    const int*   ei   = (const int*)  d_in[1];
    const float* W1_l = (const float*)d_in[2];
    const float* b1_l = (const float*)d_in[3];
    const float* W1_r = (const float*)d_in[4];
    const float* Wl1  = (const float*)d_in[5];
    const float* bl1  = (const float*)d_in[6];
    const float* W2_l = (const float*)d_in[7];
    const float* b2_l = (const float*)d_in[8];
    const float* W2_r = (const float*)d_in[9];
    float* out = (float*)d_out;

    const int N = in_sizes[0] / FDIM;   // 50000
    const int E = in_sizes[1] / 2;      // 800000

    const int* src = ei;        // edge_index[0]
    const int* dst = ei + E;    // edge_index[1]

    // carve workspace (256B-aligned regions)
    char* p = (char*)d_ws;
    auto carve = [&](size_t bytes) -> void* {
        void* r = (void*)p;
        p += (bytes + 255) & ~(size_t)255;
        return r;
    };
    int*   deg     = (int*)  carve((size_t)N * 4);
    int*   partial = (int*)  carve((size_t)N * 4);
    int*   bsum    = (int*)  carve(256 * 4);
    int*   off     = (int*)  carve((size_t)N * 4);
    int*   cursor  = (int*)  carve((size_t)N * 4);
    int*   csr     = (int*)  carve((size_t)E * 4);
    float* agg     = (float*)carve((size_t)N * FDIM * 4);
    float* h1      = (float*)carve((size_t)N * FDIM * 4);
    float* h       = (float*)carve((size_t)N * FDIM * 4);

    hipMemsetAsync(deg, 0, (size_t)N * 4, stream);

    const int gE   = (E + 255) / 256;
    const int gN   = (N + 255) / 256;
    const int gAgg = (N + 3) / 4;     // 4 waves/block, 1 node/wave
    const int gLin = (N + 63) / 64;

    // CSR build (reused by both aggregations)
    k_degree<<<gE, 256, 0, stream>>>(dst, deg, E);
    k_scan1 <<<gN, 256, 0, stream>>>(deg, partial, bsum, N);
    k_scan2 <<<1,   64, 0, stream>>>(bsum, gN);
    k_scan3 <<<gN, 256, 0, stream>>>(partial, deg, bsum, off, cursor, N);
    k_fill  <<<gE, 256, 0, stream>>>(src, dst, cursor, csr, E);

    // layer 1: h1 = relu(norm(agg1 @ W1_l^T + b1_l + x @ W1_r^T))
    k_aggregate<<<gAgg, 256, 0, stream>>>(x, csr, off, deg, agg, N);
    k_linear<128, true,  true ><<<gLin, 256, 0, stream>>>(agg, x, W1_l, W1_r, FDIM, b1_l, h1, N);

    // mid: h = relu([x, h1] @ Wl1^T + bl1)  -> split concat-weight
    k_linear<128, false, true ><<<gLin, 256, 0, stream>>>(x, h1, Wl1, Wl1 + FDIM, 2*FDIM, bl1, h, N);

    // layer 2: out = norm(agg2 @ W2_l^T + b2_l + h @ W2_r^T)
    k_aggregate<<<gAgg, 256, 0, stream>>>(h, csr, off, deg, agg, N);
    k_linear<64,  true,  false><<<gLin, 256, 0, stream>>>(agg, h, W2_l, W2_r, FDIM, b2_l, out, N);
}

// Round 2
// 412.681 us; speedup vs baseline: 1.7039x; 1.7039x over previous
//
#include <hip/hip_runtime.h>
#include <hip/hip_bf16.h>

constexpr int FDIM = 128;

typedef __attribute__((ext_vector_type(8))) short bf16x8;   // 8 bf16 = 4 VGPRs
typedef __attribute__((ext_vector_type(4))) float f32x4;

static __device__ __forceinline__ ushort f2bf(float f){
    union { float f; unsigned u; } v; v.f = f;
    unsigned r = v.u + 0x7fffu + ((v.u >> 16) & 1u);   // RNE
    return (ushort)(r >> 16);
}

// ---------------- CSR build ----------------

__global__ __launch_bounds__(256) void k_degree(const int* __restrict__ dst, int* __restrict__ deg, int E){
    int e = blockIdx.x*256 + threadIdx.x;
    if (e < E) atomicAdd(&deg[dst[e]], 1);
}

__global__ __launch_bounds__(256) void k_scan1(const int* __restrict__ deg, int* __restrict__ partial,
                                               int* __restrict__ bsum, int N){
    __shared__ int s[256];
    int i = blockIdx.x*256 + threadIdx.x;
    int v = (i < N) ? deg[i] : 0;
    s[threadIdx.x] = v;
    __syncthreads();
    for (int ofs = 1; ofs < 256; ofs <<= 1){
        int add = (threadIdx.x >= ofs) ? s[threadIdx.x - ofs] : 0;
        __syncthreads();
        s[threadIdx.x] += add;
        __syncthreads();
    }
    if (i < N) partial[i] = s[threadIdx.x];
    if (threadIdx.x == 255) bsum[blockIdx.x] = s[255];
}

__global__ void k_scan2(int* __restrict__ bsum, int nb){
    if (threadIdx.x == 0 && blockIdx.x == 0){
        int run = 0;
        for (int b = 0; b < nb; b++){ int v = bsum[b]; bsum[b] = run; run += v; }
    }
}

__global__ __launch_bounds__(256) void k_scan3(const int* __restrict__ partial, const int* __restrict__ deg,
                                               const int* __restrict__ bsum, int* __restrict__ off,
                                               int* __restrict__ cursor, int N){
    int i = blockIdx.x*256 + threadIdx.x;
    if (i < N){
        int o = partial[i] - deg[i] + bsum[blockIdx.x];  // exclusive
        off[i] = o;
        cursor[i] = o;
    }
}

__global__ __launch_bounds__(256) void k_fill(const int* __restrict__ src, const int* __restrict__ dst,
                                              int* __restrict__ cursor, int* __restrict__ csr, int E){
    int e = blockIdx.x*256 + threadIdx.x;
    if (e < E){
        int p = atomicAdd(&cursor[dst[e]], 1);
        csr[p] = src[e];
    }
}

// ---------------- fp32 -> bf16 casts ----------------

__global__ __launch_bounds__(256) void k_cast_bf16(const float* __restrict__ src, ushort* __restrict__ dst, int n){
    int i4 = (blockIdx.x*256 + threadIdx.x) * 4;
    if (i4 < n){
        float4 v = *(const float4*)(src + i4);
        ushort4 o; o.x=f2bf(v.x); o.y=f2bf(v.y); o.z=f2bf(v.z); o.w=f2bf(v.w);
        *(ushort4*)(dst + i4) = o;
    }
}

// dst[n][k] (k<256, bf16) = k<128 ? sA[n*ldA+k] : sB[n*ldB+k-128]
__global__ __launch_bounds__(256) void k_build_w(const float* __restrict__ sA, int ldA,
                                                 const float* __restrict__ sB, int ldB,
                                                 ushort* __restrict__ dst, int total){
    int i = blockIdx.x*256 + threadIdx.x;
    if (i < total){
        int nrow = i >> 8, k = i & 255;
        float v = (k < 128) ? sA[(size_t)nrow*ldA + k] : sB[(size_t)nrow*ldB + k - 128];
        dst[i] = f2bf(v);
    }
}

// ---------------- mean aggregation (bf16 feats): one wave per node ----------------

__global__ __launch_bounds__(256) void k_aggregate_bf16(
    const ushort* __restrict__ feat, const int* __restrict__ csr,
    const int* __restrict__ off, const int* __restrict__ deg,
    ushort* __restrict__ agg, int N)
{
    int node = (blockIdx.x*256 + threadIdx.x) >> 6;
    int lane = threadIdx.x & 63;
    if (node >= N) return;
    int o = off[node], d = deg[node];
    float a0 = 0.f, a1 = 0.f;
    for (int base = 0; base < d; base += 64){
        int cnt = min(64, d - base);
        int idx = (lane < cnt) ? csr[o + base + lane] : 0;   // coalesced index batch
        for (int j = 0; j < cnt; j++){
            int s = __shfl(idx, j);                          // wave-uniform broadcast
            unsigned u = *(const unsigned*)(feat + (size_t)s*FDIM + lane*2);  // 2 bf16, 256B/row/wave
            union { unsigned u; float f; } c0, c1;
            c0.u = u << 16; c1.u = u & 0xffff0000u;
            a0 += c0.f; a1 += c1.f;
        }
    }
    float inv = 1.f / (float)(d > 1 ? d : 1);
    a0 *= inv; a1 *= inv;
    unsigned r = (unsigned)f2bf(a0) | ((unsigned)f2bf(a1) << 16);
    *(unsigned*)(agg + (size_t)node*FDIM + lane*2) = r;
}

// ---------------- MFMA dual-input linear ----------------
// out[n,:] = post( [A1 | A2][n,:] @ Wb^T + bias ),  Wb: [NOUT][256] bf16
// One wave per 16 rows. A frag: A[m=lane&15][k=quad*8+j] (16B contiguous).
// B frag: B[k][n] = Wb[n][k] -> 16B contiguous from Wb row. C/D: col=lane&15, row=quad*4+reg.

template<int NOUT, bool NORM, bool RELU, bool OUTF32>
__global__ __launch_bounds__(256) void k_mfma_linear(
    const ushort* __restrict__ A1, const ushort* __restrict__ A2,
    const ushort* __restrict__ Wb, const float* __restrict__ bias,
    void* __restrict__ outv, int N)
{
    constexpr int NT = NOUT / 16;
    const int lane = threadIdx.x & 63;
    const int wid  = threadIdx.x >> 6;
    const int rowbase = blockIdx.x*64 + wid*16;
    if (rowbase >= N) return;
    const int m = lane & 15, quad = lane >> 4;
    int r = rowbase + m; if (r >= N) r = N - 1;   // clamp loads; stores masked

    const ushort* a1p = A1 + (size_t)r*FDIM + quad*8;
    const ushort* a2p = A2 + (size_t)r*FDIM + quad*8;
    const ushort* wp  = Wb + (size_t)m*256 + quad*8;

    f32x4 acc[NT];
    #pragma unroll
    for (int nt = 0; nt < NT; nt++) acc[nt] = f32x4{0.f, 0.f, 0.f, 0.f};

    #pragma unroll
    for (int kt = 0; kt < 8; kt++){
        const int kk = kt * 32;
        bf16x8 af = (kk < 128) ? *(const bf16x8*)(a1p + kk)
                               : *(const bf16x8*)(a2p + (kk - 128));
        #pragma unroll
        for (int nt = 0; nt < NT; nt++){
            bf16x8 bfr = *(const bf16x8*)(wp + (size_t)nt*16*256 + kk);
            acc[nt] = __builtin_amdgcn_mfma_f32_16x16x32_bf16(af, bfr, acc[nt], 0, 0, 0);
        }
    }

    #pragma unroll
    for (int nt = 0; nt < NT; nt++){
        float b = bias[nt*16 + m];
        acc[nt][0] += b; acc[nt][1] += b; acc[nt][2] += b; acc[nt][3] += b;
    }

    if (NORM){
        #pragma unroll
        for (int reg = 0; reg < 4; reg++){
            float ss = 0.f;
            #pragma unroll
            for (int nt = 0; nt < NT; nt++) ss += acc[nt][reg] * acc[nt][reg];
            ss += __shfl_xor(ss, 1); ss += __shfl_xor(ss, 2);
            ss += __shfl_xor(ss, 4); ss += __shfl_xor(ss, 8);   // sum over 16 lanes in quad
            float invn = 1.f / fmaxf(sqrtf(ss), 1e-12f);
            #pragma unroll
            for (int nt = 0; nt < NT; nt++) acc[nt][reg] *= invn;
        }
    }
    if (RELU){
        #pragma unroll
        for (int nt = 0; nt < NT; nt++){
            acc[nt][0] = fmaxf(acc[nt][0], 0.f); acc[nt][1] = fmaxf(acc[nt][1], 0.f);
            acc[nt][2] = fmaxf(acc[nt][2], 0.f); acc[nt][3] = fmaxf(acc[nt][3], 0.f);
        }
    }

    #pragma unroll
    for (int reg = 0; reg < 4; reg++){
        int row = rowbase + quad*4 + reg;
        if (row < N){
            if (OUTF32){
                float* o = (float*)outv + (size_t)row*NOUT + m;
                #pragma unroll
                for (int nt = 0; nt < NT; nt++) o[nt*16] = acc[nt][reg];
            } else {
                ushort* o = (ushort*)outv + (size_t)row*NOUT + m;
                #pragma unroll
                for (int nt = 0; nt < NT; nt++) o[nt*16] = f2bf(acc[nt][reg]);
            }
        }
    }
}

// ---------------- launch ----------------

extern "C" void kernel_launch(void* const* d_in, const int* in_sizes, int n_in,
                              void* d_out, int out_size, void* d_ws, size_t ws_size,
                              hipStream_t stream)
{
    const float* x    = (const float*)d_in[0];
    const int*   ei   = (const int*)  d_in[1];
    const float* W1_l = (const float*)d_in[2];
    const float* b1_l = (const float*)d_in[3];
    const float* W1_r = (const float*)d_in[4];
    const float* Wl1  = (const float*)d_in[5];
    const float* bl1  = (const float*)d_in[6];
    const float* W2_l = (const float*)d_in[7];
    const float* b2_l = (const float*)d_in[8];
    const float* W2_r = (const float*)d_in[9];
    float* out = (float*)d_out;

    const int N = in_sizes[0] / FDIM;   // 50000
    const int E = in_sizes[1] / 2;      // 800000

    const int* src = ei;
    const int* dst = ei + E;

    char* p = (char*)d_ws;
    auto carve = [&](size_t bytes) -> void* {
        void* r = (void*)p;
        p += (bytes + 255) & ~(size_t)255;
        return r;
    };
    int*    deg     = (int*)   carve((size_t)N * 4);
    int*    partial = (int*)   carve((size_t)N * 4);
    int*    bsum    = (int*)   carve(256 * 4);
    int*    off     = (int*)   carve((size_t)N * 4);
    int*    cursor  = (int*)   carve((size_t)N * 4);
    int*    csr     = (int*)   carve((size_t)E * 4);
    ushort* xb      = (ushort*)carve((size_t)N * FDIM * 2);
    ushort* h1b     = (ushort*)carve((size_t)N * FDIM * 2);
    ushort* hb      = (ushort*)carve((size_t)N * FDIM * 2);
    ushort* aggb    = (ushort*)carve((size_t)N * FDIM * 2);
    ushort* Wb1     = (ushort*)carve((size_t)128 * 256 * 2);
    ushort* Wbm     = (ushort*)carve((size_t)128 * 256 * 2);
    ushort* Wb2     = (ushort*)carve((size_t)64  * 256 * 2);

    hipMemsetAsync(deg, 0, (size_t)N * 4, stream);

    const int gE    = (E + 255) / 256;
    const int gN    = (N + 255) / 256;
    const int gAgg  = (N + 3) / 4;                       // 4 waves/block, 1 node/wave
    const int gLin  = (N + 63) / 64;                     // 4 waves/block, 16 rows/wave
    const int gCast = (N * FDIM / 4 + 255) / 256;

    // CSR build (reused by both aggregations)
    k_degree<<<gE, 256, 0, stream>>>(dst, deg, E);
    k_scan1 <<<gN, 256, 0, stream>>>(deg, partial, bsum, N);
    k_scan2 <<<1,   64, 0, stream>>>(bsum, gN);
    k_scan3 <<<gN, 256, 0, stream>>>(partial, deg, bsum, off, cursor, N);
    k_fill  <<<gE, 256, 0, stream>>>(src, dst, cursor, csr, E);

    // bf16 conversions
    k_cast_bf16<<<gCast, 256, 0, stream>>>(x, xb, N * FDIM);
    k_build_w<<<128, 256, 0, stream>>>(W1_l, 128, W1_r, 128, Wb1, 128*256);
    k_build_w<<<128, 256, 0, stream>>>(Wl1,  256, Wl1 + 128, 256, Wbm, 128*256);
    k_build_w<<< 64, 256, 0, stream>>>(W2_l, 128, W2_r, 128, Wb2,  64*256);

    // layer 1: h1 = relu(norm(agg(x) @ W1_l^T + b1_l + x @ W1_r^T))
    k_aggregate_bf16<<<gAgg, 256, 0, stream>>>(xb, csr, off, deg, aggb, N);
    k_mfma_linear<128, true,  true,  false><<<gLin, 256, 0, stream>>>(aggb, xb, Wb1, b1_l, h1b, N);

    // mid: h = relu([x | h1] @ Wl1^T + bl1)
    k_mfma_linear<128, false, true,  false><<<gLin, 256, 0, stream>>>(xb, h1b, Wbm, bl1, hb, N);

    // layer 2: out = norm(agg(h) @ W2_l^T + b2_l + h @ W2_r^T)   (fp32 out)
    k_aggregate_bf16<<<gAgg, 256, 0, stream>>>(hb, csr, off, deg, aggb, N);
    k_mfma_linear<64,  true,  false, true ><<<gLin, 256, 0, stream>>>(aggb, hb, Wb2, b2_l, out, N);
}

// Round 3
// 312.127 us; speedup vs baseline: 2.2529x; 1.3222x over previous
//
#include <hip/hip_runtime.h>
#include <hip/hip_bf16.h>

constexpr int FDIM = 128;

typedef __attribute__((ext_vector_type(8))) short bf16x8;   // 8 bf16 = 4 VGPRs
typedef __attribute__((ext_vector_type(4))) float f32x4;

static __device__ __forceinline__ ushort f2bf(float f){
    union { float f; unsigned u; } v; v.f = f;
    unsigned r = v.u + 0x7fffu + ((v.u >> 16) & 1u);   // RNE
    return (ushort)(r >> 16);
}
static __device__ __forceinline__ float bfhi(unsigned u){  // high 16 bits as bf16
    union { unsigned u; float f; } c; c.u = u & 0xffff0000u; return c.f;
}
static __device__ __forceinline__ float bflo(unsigned u){  // low 16 bits as bf16
    union { unsigned u; float f; } c; c.u = u << 16; return c.f;
}

// ---------------- CSR build ----------------

__global__ __launch_bounds__(256) void k_degree(const int* __restrict__ dst, int* __restrict__ deg, int E){
    int e = blockIdx.x*256 + threadIdx.x;
    if (e < E) atomicAdd(&deg[dst[e]], 1);
}

__global__ __launch_bounds__(256) void k_scan1(const int* __restrict__ deg, int* __restrict__ partial,
                                               int* __restrict__ bsum, int N){
    __shared__ int s[256];
    int i = blockIdx.x*256 + threadIdx.x;
    int v = (i < N) ? deg[i] : 0;
    s[threadIdx.x] = v;
    __syncthreads();
    for (int ofs = 1; ofs < 256; ofs <<= 1){
        int add = (threadIdx.x >= ofs) ? s[threadIdx.x - ofs] : 0;
        __syncthreads();
        s[threadIdx.x] += add;
        __syncthreads();
    }
    if (i < N) partial[i] = s[threadIdx.x];
    if (threadIdx.x == 255) bsum[blockIdx.x] = s[255];
}

// parallel exclusive scan of <=256 block sums, single block
__global__ __launch_bounds__(256) void k_scan2(int* __restrict__ bsum, int nb){
    __shared__ int s[256];
    int t = threadIdx.x;
    int v = (t < nb) ? bsum[t] : 0;
    s[t] = v;
    __syncthreads();
    for (int ofs = 1; ofs < 256; ofs <<= 1){
        int add = (t >= ofs) ? s[t - ofs] : 0;
        __syncthreads();
        s[t] += add;
        __syncthreads();
    }
    if (t < nb) bsum[t] = s[t] - v;   // exclusive
}

__global__ __launch_bounds__(256) void k_scan3(const int* __restrict__ partial, const int* __restrict__ deg,
                                               const int* __restrict__ bsum, int* __restrict__ off,
                                               int* __restrict__ cursor, int N){
    int i = blockIdx.x*256 + threadIdx.x;
    if (i < N){
        int o = partial[i] - deg[i] + bsum[blockIdx.x];  // exclusive
        off[i] = o;
        cursor[i] = o;
    }
}

__global__ __launch_bounds__(256) void k_fill(const int* __restrict__ src, const int* __restrict__ dst,
                                              int* __restrict__ cursor, int* __restrict__ csr, int E){
    int e = blockIdx.x*256 + threadIdx.x;
    if (e < E){
        int p = atomicAdd(&cursor[dst[e]], 1);
        csr[p] = src[e];
    }
}

// ---------------- fp32 -> bf16 casts ----------------

__global__ __launch_bounds__(256) void k_cast_bf16(const float* __restrict__ src, ushort* __restrict__ dst, int n){
    int i4 = (blockIdx.x*256 + threadIdx.x) * 4;
    if (i4 < n){
        float4 v = *(const float4*)(src + i4);
        ushort4 o; o.x=f2bf(v.x); o.y=f2bf(v.y); o.z=f2bf(v.z); o.w=f2bf(v.w);
        *(ushort4*)(dst + i4) = o;
    }
}

// build all three packed bf16 weight matrices in one launch (320 rows x 256 cols)
__global__ __launch_bounds__(256) void k_build_w3(
    const float* __restrict__ W1_l, const float* __restrict__ W1_r,
    const float* __restrict__ Wl1,
    const float* __restrict__ W2_l, const float* __restrict__ W2_r,
    ushort* __restrict__ Wb1, ushort* __restrict__ Wbm, ushort* __restrict__ Wb2)
{
    int i = blockIdx.x*256 + threadIdx.x;   // grid = 320 blocks
    int row = i >> 8, k = i & 255;
    float v; ushort* d;
    if (row < 128){
        int n = row;
        v = (k < 128) ? W1_l[(size_t)n*128 + k] : W1_r[(size_t)n*128 + k - 128];
        d = Wb1 + (size_t)n*256 + k;
    } else if (row < 256){
        int n = row - 128;
        v = Wl1[(size_t)n*256 + k];           // Wl1 is already [128][256] concat layout
        d = Wbm + (size_t)n*256 + k;
    } else {
        int n = row - 256;
        v = (k < 128) ? W2_l[(size_t)n*128 + k] : W2_r[(size_t)n*128 + k - 128];
        d = Wb2 + (size_t)n*256 + k;
    }
    *d = f2bf(v);
}

// ---------------- mean aggregation: one wave per node, 4 edges per iteration ----------------
// Wave split into 4 groups of 16 lanes; group g handles edge (4j+g); each lane loads
// 16 B (8 bf16 cols). Cross-group reduce at the end via shfl_xor(16|32).

__global__ __launch_bounds__(256) void k_aggregate_bf16(
    const ushort* __restrict__ feat, const int* __restrict__ csr,
    const int* __restrict__ off, const int* __restrict__ deg,
    ushort* __restrict__ agg, int N)
{
    int node = (blockIdx.x*256 + threadIdx.x) >> 6;
    int lane = threadIdx.x & 63;
    if (node >= N) return;
    const int grp = lane >> 4;        // which edge within quad
    const int sub = lane & 15;        // column chunk: cols [sub*8, sub*8+8)
    int o = off[node], d = deg[node];

    float a0=0.f,a1=0.f,a2=0.f,a3=0.f,a4=0.f,a5=0.f,a6=0.f,a7=0.f;

    for (int base = 0; base < d; base += 64){
        int cnt = min(64, d - base);
        int idx = (lane < cnt) ? csr[o + base + lane] : -1;   // coalesced index batch
        int iters = (cnt + 3) >> 2;
        #pragma unroll 2
        for (int j = 0; j < iters; j++){
            int s = __shfl(idx, j*4 + grp);
            unsigned msk = (s >= 0) ? 0xffffffffu : 0u;
            int sr = (s >= 0) ? s : 0;
            uint4 raw = *(const uint4*)(feat + (size_t)sr*FDIM + sub*8);
            raw.x &= msk; raw.y &= msk; raw.z &= msk; raw.w &= msk;
            a0 += bflo(raw.x); a1 += bfhi(raw.x);
            a2 += bflo(raw.y); a3 += bfhi(raw.y);
            a4 += bflo(raw.z); a5 += bfhi(raw.z);
            a6 += bflo(raw.w); a7 += bfhi(raw.w);
        }
    }

    // reduce across the 4 groups
    a0 += __shfl_xor(a0,16); a1 += __shfl_xor(a1,16); a2 += __shfl_xor(a2,16); a3 += __shfl_xor(a3,16);
    a4 += __shfl_xor(a4,16); a5 += __shfl_xor(a5,16); a6 += __shfl_xor(a6,16); a7 += __shfl_xor(a7,16);
    a0 += __shfl_xor(a0,32); a1 += __shfl_xor(a1,32); a2 += __shfl_xor(a2,32); a3 += __shfl_xor(a3,32);
    a4 += __shfl_xor(a4,32); a5 += __shfl_xor(a5,32); a6 += __shfl_xor(a6,32); a7 += __shfl_xor(a7,32);

    if (grp == 0){
        float inv = 1.f / (float)(d > 1 ? d : 1);
        uint4 r;
        r.x = (unsigned)f2bf(a0*inv) | ((unsigned)f2bf(a1*inv) << 16);
        r.y = (unsigned)f2bf(a2*inv) | ((unsigned)f2bf(a3*inv) << 16);
        r.z = (unsigned)f2bf(a4*inv) | ((unsigned)f2bf(a5*inv) << 16);
        r.w = (unsigned)f2bf(a6*inv) | ((unsigned)f2bf(a7*inv) << 16);
        *(uint4*)(agg + (size_t)node*FDIM + sub*8) = r;
    }
}

// ---------------- MFMA dual-input linear, 2 row-tiles per wave ----------------
// out[n,:] = post( [A1 | A2][n,:] @ Wb^T + bias ),  Wb: [NOUT][256] bf16
// A frag: A[m=lane&15][k=quad*8+j]; B frag: B[k][n]=Wb[n][k]; C/D: col=lane&15, row=quad*4+reg.

template<int NOUT, bool NORM, bool RELU, bool OUTF32>
__global__ __launch_bounds__(256) void k_mfma_linear(
    const ushort* __restrict__ A1, const ushort* __restrict__ A2,
    const ushort* __restrict__ Wb, const float* __restrict__ bias,
    void* __restrict__ outv, int N)
{
    constexpr int NT = NOUT / 16;
    constexpr int RT = 2;                       // row-tiles per wave
    const int lane = threadIdx.x & 63;
    const int wid  = threadIdx.x >> 6;
    const int rowbase = blockIdx.x*(64*RT) + wid*(16*RT);
    if (rowbase >= N) return;
    const int m = lane & 15, quad = lane >> 4;

    const ushort* a1p[RT];
    const ushort* a2p[RT];
    #pragma unroll
    for (int rt = 0; rt < RT; rt++){
        int r = rowbase + rt*16 + m; if (r >= N) r = N - 1;   // clamp loads; stores masked
        a1p[rt] = A1 + (size_t)r*FDIM + quad*8;
        a2p[rt] = A2 + (size_t)r*FDIM + quad*8;
    }
    const ushort* wp = Wb + (size_t)m*256 + quad*8;

    f32x4 acc[RT][NT];
    #pragma unroll
    for (int rt = 0; rt < RT; rt++)
        #pragma unroll
        for (int nt = 0; nt < NT; nt++) acc[rt][nt] = f32x4{0.f,0.f,0.f,0.f};

    #pragma unroll
    for (int kt = 0; kt < 8; kt++){
        const int kk = kt * 32;
        bf16x8 af[RT];
        #pragma unroll
        for (int rt = 0; rt < RT; rt++)
            af[rt] = (kk < 128) ? *(const bf16x8*)(a1p[rt] + kk)
                                : *(const bf16x8*)(a2p[rt] + (kk - 128));
        #pragma unroll
        for (int nt = 0; nt < NT; nt++){
            bf16x8 bfr = *(const bf16x8*)(wp + (size_t)nt*16*256 + kk);
            #pragma unroll
            for (int rt = 0; rt < RT; rt++)
                acc[rt][nt] = __builtin_amdgcn_mfma_f32_16x16x32_bf16(af[rt], bfr, acc[rt][nt], 0, 0, 0);
        }
    }

    #pragma unroll
    for (int rt = 0; rt < RT; rt++){
        #pragma unroll
        for (int nt = 0; nt < NT; nt++){
            float b = bias[nt*16 + m];
            acc[rt][nt][0] += b; acc[rt][nt][1] += b; acc[rt][nt][2] += b; acc[rt][nt][3] += b;
        }
        if (NORM){
            #pragma unroll
            for (int reg = 0; reg < 4; reg++){
                float ss = 0.f;
                #pragma unroll
                for (int nt = 0; nt < NT; nt++) ss += acc[rt][nt][reg] * acc[rt][nt][reg];
                ss += __shfl_xor(ss, 1); ss += __shfl_xor(ss, 2);
                ss += __shfl_xor(ss, 4); ss += __shfl_xor(ss, 8);
                float invn = 1.f / fmaxf(sqrtf(ss), 1e-12f);
                #pragma unroll
                for (int nt = 0; nt < NT; nt++) acc[rt][nt][reg] *= invn;
            }
        }
        if (RELU){
            #pragma unroll
            for (int nt = 0; nt < NT; nt++){
                acc[rt][nt][0] = fmaxf(acc[rt][nt][0], 0.f); acc[rt][nt][1] = fmaxf(acc[rt][nt][1], 0.f);
                acc[rt][nt][2] = fmaxf(acc[rt][nt][2], 0.f); acc[rt][nt][3] = fmaxf(acc[rt][nt][3], 0.f);
            }
        }
        #pragma unroll
        for (int reg = 0; reg < 4; reg++){
            int row = rowbase + rt*16 + quad*4 + reg;
            if (row < N){
                if (OUTF32){
                    float* o = (float*)outv + (size_t)row*NOUT + m;
                    #pragma unroll
                    for (int nt = 0; nt < NT; nt++) o[nt*16] = acc[rt][nt][reg];
                } else {
                    ushort* o = (ushort*)outv + (size_t)row*NOUT + m;
                    #pragma unroll
                    for (int nt = 0; nt < NT; nt++) o[nt*16] = f2bf(acc[rt][nt][reg]);
                }
            }
        }
    }
}

// ---------------- launch ----------------

extern "C" void kernel_launch(void* const* d_in, const int* in_sizes, int n_in,
                              void* d_out, int out_size, void* d_ws, size_t ws_size,
                              hipStream_t stream)
{
    const float* x    = (const float*)d_in[0];
    const int*   ei   = (const int*)  d_in[1];
    const float* W1_l = (const float*)d_in[2];
    const float* b1_l = (const float*)d_in[3];
    const float* W1_r = (const float*)d_in[4];
    const float* Wl1  = (const float*)d_in[5];
    const float* bl1  = (const float*)d_in[6];
    const float* W2_l = (const float*)d_in[7];
    const float* b2_l = (const float*)d_in[8];
    const float* W2_r = (const float*)d_in[9];
    float* out = (float*)d_out;

    const int N = in_sizes[0] / FDIM;   // 50000
    const int E = in_sizes[1] / 2;      // 800000

    const int* src = ei;
    const int* dst = ei + E;

    char* p = (char*)d_ws;
    auto carve = [&](size_t bytes) -> void* {
        void* r = (void*)p;
        p += (bytes + 255) & ~(size_t)255;
        return r;
    };
    int*    deg     = (int*)   carve((size_t)N * 4);
    int*    partial = (int*)   carve((size_t)N * 4);
    int*    bsum    = (int*)   carve(256 * 4);
    int*    off     = (int*)   carve((size_t)N * 4);
    int*    cursor  = (int*)   carve((size_t)N * 4);
    int*    csr     = (int*)   carve((size_t)E * 4);
    ushort* xb      = (ushort*)carve((size_t)N * FDIM * 2);
    ushort* h1b     = (ushort*)carve((size_t)N * FDIM * 2);
    ushort* hb      = (ushort*)carve((size_t)N * FDIM * 2);
    ushort* aggb    = (ushort*)carve((size_t)N * FDIM * 2);
    ushort* Wb1     = (ushort*)carve((size_t)128 * 256 * 2);
    ushort* Wbm     = (ushort*)carve((size_t)128 * 256 * 2);
    ushort* Wb2     = (ushort*)carve((size_t)64  * 256 * 2);

    hipMemsetAsync(deg, 0, (size_t)N * 4, stream);

    const int gE    = (E + 255) / 256;
    const int gN    = (N + 255) / 256;
    const int gAgg  = (N + 3) / 4;                       // 4 waves/block, 1 node/wave
    const int gLin  = (N + 127) / 128;                   // 4 waves x 32 rows
    const int gCast = (N * FDIM / 4 + 255) / 256;

    // CSR build (reused by both aggregations)
    k_degree<<<gE, 256, 0, stream>>>(dst, deg, E);
    k_scan1 <<<gN, 256, 0, stream>>>(deg, partial, bsum, N);
    k_scan2 <<<1,  256, 0, stream>>>(bsum, gN);
    k_scan3 <<<gN, 256, 0, stream>>>(partial, deg, bsum, off, cursor, N);
    k_fill  <<<gE, 256, 0, stream>>>(src, dst, cursor, csr, E);

    // bf16 conversions
    k_cast_bf16<<<gCast, 256, 0, stream>>>(x, xb, N * FDIM);
    k_build_w3<<<320, 256, 0, stream>>>(W1_l, W1_r, Wl1, W2_l, W2_r, Wb1, Wbm, Wb2);

    // layer 1: h1 = relu(norm(agg(x) @ W1_l^T + b1_l + x @ W1_r^T))
    k_aggregate_bf16<<<gAgg, 256, 0, stream>>>(xb, csr, off, deg, aggb, N);
    k_mfma_linear<128, true,  true,  false><<<gLin, 256, 0, stream>>>(aggb, xb, Wb1, b1_l, h1b, N);

    // mid: h = relu([x | h1] @ Wl1^T + bl1)
    k_mfma_linear<128, false, true,  false><<<gLin, 256, 0, stream>>>(xb, h1b, Wbm, bl1, hb, N);

    // layer 2: out = norm(agg(h) @ W2_l^T + b2_l + h @ W2_r^T)   (fp32 out)
    k_aggregate_bf16<<<gAgg, 256, 0, stream>>>(hb, csr, off, deg, aggb, N);
    k_mfma_linear<64,  true,  false, true ><<<gLin, 256, 0, stream>>>(aggb, hb, Wb2, b2_l, out, N);
}

// Round 4
// 297.523 us; speedup vs baseline: 2.3635x; 1.0491x over previous
//
#include <hip/hip_runtime.h>
#include <hip/hip_bf16.h>

constexpr int FDIM = 128;

typedef __attribute__((ext_vector_type(8))) short bf16x8;   // 8 bf16 = 4 VGPRs
typedef __attribute__((ext_vector_type(4))) float f32x4;

static __device__ __forceinline__ ushort f2bf(float f){
    union { float f; unsigned u; } v; v.f = f;
    unsigned r = v.u + 0x7fffu + ((v.u >> 16) & 1u);   // RNE
    return (ushort)(r >> 16);
}
static __device__ __forceinline__ float bfhi(unsigned u){
    union { unsigned u; float f; } c; c.u = u & 0xffff0000u; return c.f;
}
static __device__ __forceinline__ float bflo(unsigned u){
    union { unsigned u; float f; } c; c.u = u << 16; return c.f;
}

// ---------------- CSR build ----------------

// fused degree + per-edge rank (rank = slot within the node's csr segment)
__global__ __launch_bounds__(256) void k_degree_rank(const int* __restrict__ dst, int* __restrict__ deg,
                                                     int* __restrict__ rank, int E){
    int e = blockIdx.x*256 + threadIdx.x;
    if (e < E) rank[e] = atomicAdd(&deg[dst[e]], 1);
}

__global__ __launch_bounds__(256) void k_scan1(const int* __restrict__ deg, int* __restrict__ partial,
                                               int* __restrict__ bsum, int N){
    __shared__ int s[256];
    int i = blockIdx.x*256 + threadIdx.x;
    int v = (i < N) ? deg[i] : 0;
    s[threadIdx.x] = v;
    __syncthreads();
    for (int ofs = 1; ofs < 256; ofs <<= 1){
        int add = (threadIdx.x >= ofs) ? s[threadIdx.x - ofs] : 0;
        __syncthreads();
        s[threadIdx.x] += add;
        __syncthreads();
    }
    if (i < N) partial[i] = s[threadIdx.x];
    if (threadIdx.x == 255) bsum[blockIdx.x] = s[255];
}

// parallel exclusive scan of <=256 block sums, single block
__global__ __launch_bounds__(256) void k_scan2(int* __restrict__ bsum, int nb){
    __shared__ int s[256];
    int t = threadIdx.x;
    int v = (t < nb) ? bsum[t] : 0;
    s[t] = v;
    __syncthreads();
    for (int ofs = 1; ofs < 256; ofs <<= 1){
        int add = (t >= ofs) ? s[t - ofs] : 0;
        __syncthreads();
        s[t] += add;
        __syncthreads();
    }
    if (t < nb) bsum[t] = s[t] - v;   // exclusive
}

__global__ __launch_bounds__(256) void k_scan3(const int* __restrict__ partial, const int* __restrict__ deg,
                                               const int* __restrict__ bsum, int* __restrict__ off, int N){
    int i = blockIdx.x*256 + threadIdx.x;
    if (i < N) off[i] = partial[i] - deg[i] + bsum[blockIdx.x];  // exclusive
}

// windowed fill: 8 dst-windows; window = blockIdx&7 (round-robin -> one XCD per window,
// heuristic only; correctness independent of dispatch). No atomics: slot = off[d] + rank[e].
__global__ __launch_bounds__(256) void k_fill_win(const int* __restrict__ src, const int* __restrict__ dst,
                                                  const int* __restrict__ rank, const int* __restrict__ off,
                                                  int* __restrict__ csr, int E, int WINW){
    const int win   = blockIdx.x & 7;
    const int slice = blockIdx.x >> 3;           // 64 slices
    const int lo = win * WINW, hi = lo + WINW;
    const int ES = (E + 63) >> 6;
    const int e0 = slice * ES, e1 = min(E, e0 + ES);
    for (int e = e0 + (int)threadIdx.x; e < e1; e += 256){
        int d = dst[e];
        if (d >= lo && d < hi)
            csr[off[d] + rank[e]] = src[e];
    }
}

// ---------------- fp32 -> bf16 casts ----------------

__global__ __launch_bounds__(256) void k_cast_bf16(const float* __restrict__ src, ushort* __restrict__ dst, int n){
    int i4 = (blockIdx.x*256 + threadIdx.x) * 4;
    if (i4 < n){
        float4 v = *(const float4*)(src + i4);
        ushort4 o; o.x=f2bf(v.x); o.y=f2bf(v.y); o.z=f2bf(v.z); o.w=f2bf(v.w);
        *(ushort4*)(dst + i4) = o;
    }
}

// build all three packed bf16 weight matrices in one launch (320 rows x 256 cols)
__global__ __launch_bounds__(256) void k_build_w3(
    const float* __restrict__ W1_l, const float* __restrict__ W1_r,
    const float* __restrict__ Wl1,
    const float* __restrict__ W2_l, const float* __restrict__ W2_r,
    ushort* __restrict__ Wb1, ushort* __restrict__ Wbm, ushort* __restrict__ Wb2)
{
    int i = blockIdx.x*256 + threadIdx.x;   // grid = 320 blocks
    int row = i >> 8, k = i & 255;
    float v; ushort* d;
    if (row < 128){
        int n = row;
        v = (k < 128) ? W1_l[(size_t)n*128 + k] : W1_r[(size_t)n*128 + k - 128];
        d = Wb1 + (size_t)n*256 + k;
    } else if (row < 256){
        int n = row - 128;
        v = Wl1[(size_t)n*256 + k];
        d = Wbm + (size_t)n*256 + k;
    } else {
        int n = row - 256;
        v = (k < 128) ? W2_l[(size_t)n*128 + k] : W2_r[(size_t)n*128 + k - 128];
        d = Wb2 + (size_t)n*256 + k;
    }
    *d = f2bf(v);
}

// ---------------- mean aggregation: one wave per node, 4 edges per iteration ----------------

__global__ __launch_bounds__(256) void k_aggregate_bf16(
    const ushort* __restrict__ feat, const int* __restrict__ csr,
    const int* __restrict__ off, const int* __restrict__ deg,
    ushort* __restrict__ agg, int N)
{
    int node = (blockIdx.x*256 + threadIdx.x) >> 6;
    int lane = threadIdx.x & 63;
    if (node >= N) return;
    const int grp = lane >> 4;
    const int sub = lane & 15;
    int o = off[node], d = deg[node];

    float a0=0.f,a1=0.f,a2=0.f,a3=0.f,a4=0.f,a5=0.f,a6=0.f,a7=0.f;

    for (int base = 0; base < d; base += 64){
        int cnt = min(64, d - base);
        int idx = (lane < cnt) ? csr[o + base + lane] : -1;
        int iters = (cnt + 3) >> 2;
        #pragma unroll 2
        for (int j = 0; j < iters; j++){
            int s = __shfl(idx, j*4 + grp);
            unsigned msk = (s >= 0) ? 0xffffffffu : 0u;
            int sr = (s >= 0) ? s : 0;
            uint4 raw = *(const uint4*)(feat + (size_t)sr*FDIM + sub*8);
            raw.x &= msk; raw.y &= msk; raw.z &= msk; raw.w &= msk;
            a0 += bflo(raw.x); a1 += bfhi(raw.x);
            a2 += bflo(raw.y); a3 += bfhi(raw.y);
            a4 += bflo(raw.z); a5 += bfhi(raw.z);
            a6 += bflo(raw.w); a7 += bfhi(raw.w);
        }
    }

    a0 += __shfl_xor(a0,16); a1 += __shfl_xor(a1,16); a2 += __shfl_xor(a2,16); a3 += __shfl_xor(a3,16);
    a4 += __shfl_xor(a4,16); a5 += __shfl_xor(a5,16); a6 += __shfl_xor(a6,16); a7 += __shfl_xor(a7,16);
    a0 += __shfl_xor(a0,32); a1 += __shfl_xor(a1,32); a2 += __shfl_xor(a2,32); a3 += __shfl_xor(a3,32);
    a4 += __shfl_xor(a4,32); a5 += __shfl_xor(a5,32); a6 += __shfl_xor(a6,32); a7 += __shfl_xor(a7,32);

    if (grp == 0){
        float inv = 1.f / (float)(d > 1 ? d : 1);
        uint4 r;
        r.x = (unsigned)f2bf(a0*inv) | ((unsigned)f2bf(a1*inv) << 16);
        r.y = (unsigned)f2bf(a2*inv) | ((unsigned)f2bf(a3*inv) << 16);
        r.z = (unsigned)f2bf(a4*inv) | ((unsigned)f2bf(a5*inv) << 16);
        r.w = (unsigned)f2bf(a6*inv) | ((unsigned)f2bf(a7*inv) << 16);
        *(uint4*)(agg + (size_t)node*FDIM + sub*8) = r;
    }
}

// ---------------- MFMA dual-input linear, 2 row-tiles per wave ----------------

template<int NOUT, bool NORM, bool RELU, bool OUTF32>
__global__ __launch_bounds__(256) void k_mfma_linear(
    const ushort* __restrict__ A1, const ushort* __restrict__ A2,
    const ushort* __restrict__ Wb, const float* __restrict__ bias,
    void* __restrict__ outv, int N)
{
    constexpr int NT = NOUT / 16;
    constexpr int RT = 2;
    const int lane = threadIdx.x & 63;
    const int wid  = threadIdx.x >> 6;
    const int rowbase = blockIdx.x*(64*RT) + wid*(16*RT);
    if (rowbase >= N) return;
    const int m = lane & 15, quad = lane >> 4;

    const ushort* a1p[RT];
    const ushort* a2p[RT];
    #pragma unroll
    for (int rt = 0; rt < RT; rt++){
        int r = rowbase + rt*16 + m; if (r >= N) r = N - 1;
        a1p[rt] = A1 + (size_t)r*FDIM + quad*8;
        a2p[rt] = A2 + (size_t)r*FDIM + quad*8;
    }
    const ushort* wp = Wb + (size_t)m*256 + quad*8;

    f32x4 acc[RT][NT];
    #pragma unroll
    for (int rt = 0; rt < RT; rt++)
        #pragma unroll
        for (int nt = 0; nt < NT; nt++) acc[rt][nt] = f32x4{0.f,0.f,0.f,0.f};

    #pragma unroll
    for (int kt = 0; kt < 8; kt++){
        const int kk = kt * 32;
        bf16x8 af[RT];
        #pragma unroll
        for (int rt = 0; rt < RT; rt++)
            af[rt] = (kk < 128) ? *(const bf16x8*)(a1p[rt] + kk)
                                : *(const bf16x8*)(a2p[rt] + (kk - 128));
        #pragma unroll
        for (int nt = 0; nt < NT; nt++){
            bf16x8 bfr = *(const bf16x8*)(wp + (size_t)nt*16*256 + kk);
            #pragma unroll
            for (int rt = 0; rt < RT; rt++)
                acc[rt][nt] = __builtin_amdgcn_mfma_f32_16x16x32_bf16(af[rt], bfr, acc[rt][nt], 0, 0, 0);
        }
    }

    #pragma unroll
    for (int rt = 0; rt < RT; rt++){
        #pragma unroll
        for (int nt = 0; nt < NT; nt++){
            float b = bias[nt*16 + m];
            acc[rt][nt][0] += b; acc[rt][nt][1] += b; acc[rt][nt][2] += b; acc[rt][nt][3] += b;
        }
        if (NORM){
            #pragma unroll
            for (int reg = 0; reg < 4; reg++){
                float ss = 0.f;
                #pragma unroll
                for (int nt = 0; nt < NT; nt++) ss += acc[rt][nt][reg] * acc[rt][nt][reg];
                ss += __shfl_xor(ss, 1); ss += __shfl_xor(ss, 2);
                ss += __shfl_xor(ss, 4); ss += __shfl_xor(ss, 8);
                float invn = 1.f / fmaxf(sqrtf(ss), 1e-12f);
                #pragma unroll
                for (int nt = 0; nt < NT; nt++) acc[rt][nt][reg] *= invn;
            }
        }
        if (RELU){
            #pragma unroll
            for (int nt = 0; nt < NT; nt++){
                acc[rt][nt][0] = fmaxf(acc[rt][nt][0], 0.f); acc[rt][nt][1] = fmaxf(acc[rt][nt][1], 0.f);
                acc[rt][nt][2] = fmaxf(acc[rt][nt][2], 0.f); acc[rt][nt][3] = fmaxf(acc[rt][nt][3], 0.f);
            }
        }
        #pragma unroll
        for (int reg = 0; reg < 4; reg++){
            int row = rowbase + rt*16 + quad*4 + reg;
            if (row < N){
                if (OUTF32){
                    float* o = (float*)outv + (size_t)row*NOUT + m;
                    #pragma unroll
                    for (int nt = 0; nt < NT; nt++) o[nt*16] = acc[rt][nt][reg];
                } else {
                    ushort* o = (ushort*)outv + (size_t)row*NOUT + m;
                    #pragma unroll
                    for (int nt = 0; nt < NT; nt++) o[nt*16] = f2bf(acc[rt][nt][reg]);
                }
            }
        }
    }
}

// ---------------- launch ----------------

extern "C" void kernel_launch(void* const* d_in, const int* in_sizes, int n_in,
                              void* d_out, int out_size, void* d_ws, size_t ws_size,
                              hipStream_t stream)
{
    const float* x    = (const float*)d_in[0];
    const int*   ei   = (const int*)  d_in[1];
    const float* W1_l = (const float*)d_in[2];
    const float* b1_l = (const float*)d_in[3];
    const float* W1_r = (const float*)d_in[4];
    const float* Wl1  = (const float*)d_in[5];
    const float* bl1  = (const float*)d_in[6];
    const float* W2_l = (const float*)d_in[7];
    const float* b2_l = (const float*)d_in[8];
    const float* W2_r = (const float*)d_in[9];
    float* out = (float*)d_out;

    const int N = in_sizes[0] / FDIM;   // 50000
    const int E = in_sizes[1] / 2;      // 800000

    const int* src = ei;
    const int* dst = ei + E;

    char* p = (char*)d_ws;
    auto carve = [&](size_t bytes) -> void* {
        void* r = (void*)p;
        p += (bytes + 255) & ~(size_t)255;
        return r;
    };
    int*    deg     = (int*)   carve((size_t)N * 4);
    int*    partial = (int*)   carve((size_t)N * 4);
    int*    bsum    = (int*)   carve(256 * 4);
    int*    off     = (int*)   carve((size_t)N * 4);
    int*    rank    = (int*)   carve((size_t)E * 4);
    int*    csr     = (int*)   carve((size_t)E * 4);
    ushort* xb      = (ushort*)carve((size_t)N * FDIM * 2);
    ushort* h1b     = (ushort*)carve((size_t)N * FDIM * 2);
    ushort* hb      = (ushort*)carve((size_t)N * FDIM * 2);
    ushort* aggb    = (ushort*)carve((size_t)N * FDIM * 2);
    ushort* Wb1     = (ushort*)carve((size_t)128 * 256 * 2);
    ushort* Wbm     = (ushort*)carve((size_t)128 * 256 * 2);
    ushort* Wb2     = (ushort*)carve((size_t)64  * 256 * 2);

    hipMemsetAsync(deg, 0, (size_t)N * 4, stream);

    const int gE    = (E + 255) / 256;
    const int gN    = (N + 255) / 256;
    const int gAgg  = (N + 3) / 4;
    const int gLin  = (N + 127) / 128;
    const int gCast = (N * FDIM / 4 + 255) / 256;
    const int WINW  = (N + 7) / 8;

    // CSR build (reused by both aggregations)
    k_degree_rank<<<gE, 256, 0, stream>>>(dst, deg, rank, E);
    k_scan1 <<<gN, 256, 0, stream>>>(deg, partial, bsum, N);
    k_scan2 <<<1,  256, 0, stream>>>(bsum, gN);
    k_scan3 <<<gN, 256, 0, stream>>>(partial, deg, bsum, off, N);
    k_fill_win<<<512, 256, 0, stream>>>(src, dst, rank, off, csr, E, WINW);

    // bf16 conversions
    k_cast_bf16<<<gCast, 256, 0, stream>>>(x, xb, N * FDIM);
    k_build_w3<<<320, 256, 0, stream>>>(W1_l, W1_r, Wl1, W2_l, W2_r, Wb1, Wbm, Wb2);

    // layer 1: h1 = relu(norm(agg(x) @ W1_l^T + b1_l + x @ W1_r^T))
    k_aggregate_bf16<<<gAgg, 256, 0, stream>>>(xb, csr, off, deg, aggb, N);
    k_mfma_linear<128, true,  true,  false><<<gLin, 256, 0, stream>>>(aggb, xb, Wb1, b1_l, h1b, N);

    // mid: h = relu([x | h1] @ Wl1^T + bl1)
    k_mfma_linear<128, false, true,  false><<<gLin, 256, 0, stream>>>(xb, h1b, Wbm, bl1, hb, N);

    // layer 2: out = norm(agg(h) @ W2_l^T + b2_l + h @ W2_r^T)   (fp32 out)
    k_aggregate_bf16<<<gAgg, 256, 0, stream>>>(hb, csr, off, deg, aggb, N);
    k_mfma_linear<64,  true,  false, true ><<<gLin, 256, 0, stream>>>(aggb, hb, Wb2, b2_l, out, N);
}